// Round 1
// baseline (428.344 us; speedup 1.0000x reference)
//
#include <hip/hip_runtime.h>
#include <math.h>

#define BB   2
#define NN   8192
#define SS   1024
#define KK   32
#define HID  256
#define NTH  256
#define PPT  (NN/NTH)   // 32 candidate points per thread

__global__ __launch_bounds__(NTH, 4)
void snp_kernel(const float* __restrict__ pos,     // (B,N,3)
                const int*   __restrict__ snidx,   // (S,)
                const float* __restrict__ w_in,    // (3,HID)
                const float* __restrict__ b_in,    // (HID,)
                const float* __restrict__ w1,      // (HID,HID)
                const float* __restrict__ b1,      // (HID,)
                const float* __restrict__ w2,      // (HID,HID)
                const float* __restrict__ b2,      // (HID,)
                float*       __restrict__ out)     // (B,S,HID)
{
    const int bs = blockIdx.x;          // 0 .. B*S-1
    const int b  = bs / SS;
    const int s  = bs - b * SS;
    const int t  = threadIdx.x;

    __shared__ __align__(16) float h0[KK][HID];   // 32 KB, reused for gelu out
    __shared__ unsigned long long red[4];
    __shared__ int   nbr[KK];
    __shared__ float nbc[KK][3];

    const float* posb = pos + (size_t)b * (NN * 3);
    const int   sp = snidx[s];
    const float sx = posb[sp*3 + 0];
    const float sy = posb[sp*3 + 1];
    const float sz = posb[sp*3 + 2];

    // ---- Phase 1: distances, packed (dist_bits, index) keys in registers ----
    // Replicate reference rounding exactly: no fma contraction, ((dx^2+dy^2)+dz^2), IEEE sqrt.
    unsigned long long keys[PPT];
#pragma unroll
    for (int c = 0; c < PPT; ++c) {
        const int i = t + c * NTH;                 // coalesced across lanes
        const float dx = __fsub_rn(sx, posb[i*3 + 0]);
        const float dy = __fsub_rn(sy, posb[i*3 + 1]);
        const float dz = __fsub_rn(sz, posb[i*3 + 2]);
        const float sq = __fadd_rn(__fadd_rn(__fmul_rn(dx,dx), __fmul_rn(dy,dy)),
                                   __fmul_rn(dz,dz));
        const float d  = __fsqrt_rn(sq);
        keys[c] = ((unsigned long long)__float_as_uint(d) << 32) | (unsigned)i;
    }
    unsigned long long lmin = keys[0];
#pragma unroll
    for (int c = 1; c < PPT; ++c) lmin = keys[c] < lmin ? keys[c] : lmin;

    // ---- Phase 2: 32 sequential min-extractions (stable-argsort semantics) ----
    for (int it = 0; it < KK; ++it) {
        unsigned long long m = lmin;
#pragma unroll
        for (int off = 32; off > 0; off >>= 1) {
            const unsigned long long o = __shfl_xor(m, off, 64);
            m = o < m ? o : m;
        }
        if ((t & 63) == 0) red[t >> 6] = m;
        __syncthreads();
        const unsigned long long r0 = red[0] < red[1] ? red[0] : red[1];
        const unsigned long long r1 = red[2] < red[3] ? red[2] : red[3];
        const unsigned long long w  = r0 < r1 ? r0 : r1;
        if (t == 0) nbr[it] = (int)(unsigned)w;
        if (lmin == w) {                            // unique owner (index in key)
#pragma unroll
            for (int c = 0; c < PPT; ++c) if (keys[c] == w) keys[c] = ~0ULL;
            lmin = keys[0];
#pragma unroll
            for (int c = 1; c < PPT; ++c) lmin = keys[c] < lmin ? keys[c] : lmin;
        }
        __syncthreads();                            // protects red[] + nbr[]
    }

    // ---- Phase 3: gather neighbor coords ----
    if (t < KK * 3) {
        const int k = t / 3, d = t - 3 * k;
        nbc[k][d] = posb[(size_t)nbr[k] * 3 + d];
    }
    __syncthreads();

    // ---- Phase 4: h0 = coords @ w_in + b_in + sincos PE (thread = channel c) ----
    const int  c     = t;
    const int  dimi  = c / 84;                      // 84 = 2*42 channels per dim
    const int  cc    = c - dimi * 84;
    const bool hasPe = c < 252;
    const bool isCos = cc >= 42;
    const int  f     = isCos ? cc - 42 : cc;
    const float fcoef = (float)(-9.210340371976184 / 41.0);  // -ln(1e4)/(half-1)
    const float freqv = expf((float)f * fcoef);
    const int  di    = hasPe ? dimi : 0;

    const float wi0 = w_in[0*HID + c];
    const float wi1 = w_in[1*HID + c];
    const float wi2 = w_in[2*HID + c];
    const float bi  = b_in[c];

#pragma unroll
    for (int k = 0; k < KK; ++k) {
        const float x0 = nbc[k][0], x1 = nbc[k][1], x2 = nbc[k][2];
        float v = fmaf(x2, wi2, fmaf(x1, wi1, fmaf(x0, wi0, bi)));
        if (hasPe) {
            const float xv  = (di == 0) ? x0 : ((di == 1) ? x1 : x2);
            const float ang = xv * freqv;
            v += isCos ? cosf(ang) : sinf(ang);
        }
        h0[k][c] = v;                               // bank = c%32 -> conflict-free
    }
    __syncthreads();

    // ---- Phase 5: layer 1 (h0 @ w1 + b1), tanh-gelu ----
    float acc[KK];
    const float b1v = b1[c];
#pragma unroll
    for (int k = 0; k < KK; ++k) acc[k] = b1v;
    for (int j = 0; j < HID; j += 4) {
        const float wa = w1[(j+0)*HID + c];          // coalesced, L2-resident
        const float wb = w1[(j+1)*HID + c];
        const float wc = w1[(j+2)*HID + c];
        const float wd = w1[(j+3)*HID + c];
#pragma unroll
        for (int k = 0; k < KK; ++k) {
            const float4 hv = *(const float4*)&h0[k][j];   // LDS broadcast read
            float a = acc[k];
            a = fmaf(hv.x, wa, a);
            a = fmaf(hv.y, wb, a);
            a = fmaf(hv.z, wc, a);
            a = fmaf(hv.w, wd, a);
            acc[k] = a;
        }
    }
    __syncthreads();                                 // all h0 reads done
    const float kA = 0.7978845608028654f;            // sqrt(2/pi)
#pragma unroll
    for (int k = 0; k < KK; ++k) {
        const float x  = acc[k];
        const float x3 = x * x * x;
        const float tv = tanhf(kA * fmaf(0.044715f, x3, x));
        h0[k][c] = 0.5f * x * (1.0f + tv);           // reuse h0 as gelu output
    }
    __syncthreads();

    // ---- Phase 6: layer 2 (@ w2 + b2) fused with mean over K ----
#pragma unroll
    for (int k = 0; k < KK; ++k) acc[k] = 0.0f;      // 32 independent chains (ILP)
    for (int j = 0; j < HID; j += 4) {
        const float wa = w2[(j+0)*HID + c];
        const float wb = w2[(j+1)*HID + c];
        const float wc = w2[(j+2)*HID + c];
        const float wd = w2[(j+3)*HID + c];
#pragma unroll
        for (int k = 0; k < KK; ++k) {
            const float4 hv = *(const float4*)&h0[k][j];
            float a = acc[k];
            a = fmaf(hv.x, wa, a);
            a = fmaf(hv.y, wb, a);
            a = fmaf(hv.z, wc, a);
            a = fmaf(hv.w, wd, a);
            acc[k] = a;
        }
    }
    float tot = 0.0f;
#pragma unroll
    for (int k = 0; k < KK; ++k) tot += acc[k];
    out[(size_t)bs * HID + c] = fmaf(tot, 1.0f / KK, b2[c]);
}

extern "C" void kernel_launch(void* const* d_in, const int* in_sizes, int n_in,
                              void* d_out, int out_size, void* d_ws, size_t ws_size,
                              hipStream_t stream) {
    const float* pos  = (const float*)d_in[0];
    const int*   sni  = (const int*)  d_in[1];
    const float* w_in = (const float*)d_in[2];
    const float* b_in = (const float*)d_in[3];
    const float* w1   = (const float*)d_in[4];
    const float* b1   = (const float*)d_in[5];
    const float* w2   = (const float*)d_in[6];
    const float* b2   = (const float*)d_in[7];
    float* out = (float*)d_out;

    dim3 grid(BB * SS), block(NTH);
    hipLaunchKernelGGL(snp_kernel, grid, block, 0, stream,
                       pos, sni, w_in, b_in, w1, b1, w2, b2, out);
}

// Round 2
// 295.401 us; speedup vs baseline: 1.4500x; 1.4500x over previous
//
#include <hip/hip_runtime.h>
#include <math.h>

#define BB   2
#define NN   8192
#define SS   1024
#define KK   32
#define HID  256
#define NTH  256
#define PPT  (NN/NTH)   // 32 candidate points per thread

// float4 component by constant index (folds under full unroll)
#define F4C(v, i) ((i)==0?(v).x:((i)==1?(v).y:((i)==2?(v).z:(v).w)))

__global__ __launch_bounds__(NTH, 5)
void snp_kernel(const float* __restrict__ pos,     // (B,N,3)
                const int*   __restrict__ snidx,   // (S,)
                const float* __restrict__ w_in,    // (3,HID)
                const float* __restrict__ b_in,    // (HID,)
                const float* __restrict__ w1,      // (HID,HID)
                const float* __restrict__ b1,      // (HID,)
                const float* __restrict__ w2,      // (HID,HID)
                const float* __restrict__ b2,      // (HID,)
                float*       __restrict__ out)     // (B,S,HID)
{
    const int bs = blockIdx.x;          // 0 .. B*S-1
    const int b  = bs / SS;
    const int s  = bs - b * SS;
    const int t  = threadIdx.x;

    // Exactly 32 KB of LDS -> 5 blocks/CU. KNN scratch lives inside rows 30/31
    // of h0 (unused until phase 4; protected by barriers at the k=31 write).
    __shared__ __align__(16) float h0[KK][HID];
    unsigned long long* red = (unsigned long long*)&h0[30][0];  // 4 u64  (32 B)
    int*   nbr = (int*)&h0[30][8];                              // 32 int (128 B)
    float* nbc = &h0[31][0];                                    // 96 f32 (384 B)

    const float* posb = pos + (size_t)b * (NN * 3);
    const int   sp = snidx[s];
    const float sx = posb[sp*3 + 0];
    const float sy = posb[sp*3 + 1];
    const float sz = posb[sp*3 + 2];

    // ---- Phase 1: distances, packed (dist_bits, index) keys in registers ----
    unsigned long long keys[PPT];
#pragma unroll
    for (int c = 0; c < PPT; ++c) {
        const int i = t + c * NTH;                 // coalesced across lanes
        const float dx = __fsub_rn(sx, posb[i*3 + 0]);
        const float dy = __fsub_rn(sy, posb[i*3 + 1]);
        const float dz = __fsub_rn(sz, posb[i*3 + 2]);
        const float sq = __fadd_rn(__fadd_rn(__fmul_rn(dx,dx), __fmul_rn(dy,dy)),
                                   __fmul_rn(dz,dz));
        const float d  = __fsqrt_rn(sq);
        keys[c] = ((unsigned long long)__float_as_uint(d) << 32) | (unsigned)i;
    }
    unsigned long long lmin = keys[0];
#pragma unroll
    for (int c = 1; c < PPT; ++c) lmin = keys[c] < lmin ? keys[c] : lmin;

    // ---- Phase 2: 32 sequential min-extractions (stable-argsort semantics) ----
    for (int it = 0; it < KK; ++it) {
        unsigned long long m = lmin;
#pragma unroll
        for (int off = 32; off > 0; off >>= 1) {
            const unsigned long long o = __shfl_xor(m, off, 64);
            m = o < m ? o : m;
        }
        if ((t & 63) == 0) red[t >> 6] = m;
        __syncthreads();
        const unsigned long long r0 = red[0] < red[1] ? red[0] : red[1];
        const unsigned long long r1 = red[2] < red[3] ? red[2] : red[3];
        const unsigned long long w  = r0 < r1 ? r0 : r1;
        if (t == 0) nbr[it] = (int)(unsigned)w;
        if (lmin == w) {                            // unique owner invalidates
#pragma unroll
            for (int c = 0; c < PPT; ++c) if (keys[c] == w) keys[c] = ~0ULL;
            lmin = keys[0];
#pragma unroll
            for (int c = 1; c < PPT; ++c) lmin = keys[c] < lmin ? keys[c] : lmin;
        }
        __syncthreads();                            // protects red[] + nbr[]
    }

    // ---- Phase 3: gather neighbor coords into nbc (row 31 of h0) ----
    if (t < KK * 3) {
        nbc[t] = posb[(size_t)nbr[t / 3] * 3 + (t % 3)];
    }
    __syncthreads();

    // ---- Phase 4: h0 = coords @ w_in + b_in + sincos PE (thread = channel c) ----
    {
        const int  c     = t;
        const int  dimi  = c / 84;                  // 84 = 2*42 channels per dim
        const int  cc    = c - dimi * 84;
        const bool hasPe = c < 252;
        const bool isCos = cc >= 42;
        const int  f     = isCos ? cc - 42 : cc;
        const float fcoef = (float)(-9.210340371976184 / 41.0);
        const float freqv = expf((float)f * fcoef);
        const int  di    = hasPe ? dimi : 0;

        const float wi0 = w_in[0*HID + c];
        const float wi1 = w_in[1*HID + c];
        const float wi2 = w_in[2*HID + c];
        const float bi  = b_in[c];

        auto h0val = [&](float x0, float x1, float x2) -> float {
            float v = fmaf(x2, wi2, fmaf(x1, wi1, fmaf(x0, wi0, bi)));
            if (hasPe) {
                const float xv  = (di == 0) ? x0 : ((di == 1) ? x1 : x2);
                const float ang = xv * freqv;
                v += isCos ? cosf(ang) : sinf(ang);
            }
            return v;
        };

        // rows 0..30: nbc (row 31) untouched; k=30 write clobbers red/nbr (dead)
#pragma unroll 4
        for (int k = 0; k < KK - 1; ++k) {
            const float x0 = nbc[3*k+0], x1 = nbc[3*k+1], x2 = nbc[3*k+2];
            h0[k][c] = h0val(x0, x1, x2);
        }
        // k=31: its coords live where row 31 will be written -> stage via regs
        __syncthreads();
        const float x0 = nbc[93], x1 = nbc[94], x2 = nbc[95];
        __syncthreads();
        h0[KK-1][c] = h0val(x0, x1, x2);
    }
    __syncthreads();

    // ---- MLP: register-tiled. thread = 4 contiguous channels x 8 k-rows ----
    const int ct = t & 63;           // c-tile
    const int kt = t >> 6;           // k-group (wave-uniform)
    const int cb = ct * 4;
    const int kb = kt * 8;

    float acc[4][8];

    // ---- Phase 5: layer 1 (h0 @ w1 + b1) ----
    {
        const float4 bv = *(const float4*)&b1[cb];
#pragma unroll
        for (int ci = 0; ci < 4; ++ci)
#pragma unroll
            for (int kk = 0; kk < 8; ++kk) acc[ci][kk] = F4C(bv, ci);

        for (int j = 0; j < HID; j += 4) {
            float4 h[8];
#pragma unroll
            for (int kk = 0; kk < 8; ++kk)
                h[kk] = *(const float4*)&h0[kb + kk][j];    // broadcast b128
            float4 w[4];
#pragma unroll
            for (int jj = 0; jj < 4; ++jj)
                w[jj] = *(const float4*)&w1[(j + jj)*HID + cb];  // coalesced
#pragma unroll
            for (int jj = 0; jj < 4; ++jj)
#pragma unroll
                for (int ci = 0; ci < 4; ++ci) {
                    const float wv = F4C(w[jj], ci);
#pragma unroll
                    for (int kk = 0; kk < 8; ++kk)
                        acc[ci][kk] = fmaf(F4C(h[kk], jj), wv, acc[ci][kk]);
                }
        }
    }
    __syncthreads();                                 // all h0 reads done

    // gelu (tanh approx), write back into h0
    {
        const float kA = 0.7978845608028654f;        // sqrt(2/pi)
#pragma unroll
        for (int kk = 0; kk < 8; ++kk) {
            float4 g;
#pragma unroll
            for (int ci = 0; ci < 4; ++ci) {
                const float x  = acc[ci][kk];
                const float x3 = x * x * x;
                const float tv = tanhf(kA * fmaf(0.044715f, x3, x));
                const float gv = 0.5f * x * (1.0f + tv);
                if (ci == 0) g.x = gv; else if (ci == 1) g.y = gv;
                else if (ci == 2) g.z = gv; else g.w = gv;
            }
            *(float4*)&h0[kb + kk][cb] = g;
        }
    }
    __syncthreads();

    // ---- Phase 6: layer 2 (@ w2), partial over this thread's 8 k-rows ----
    {
#pragma unroll
        for (int ci = 0; ci < 4; ++ci)
#pragma unroll
            for (int kk = 0; kk < 8; ++kk) acc[ci][kk] = 0.0f;

        for (int j = 0; j < HID; j += 4) {
            float4 h[8];
#pragma unroll
            for (int kk = 0; kk < 8; ++kk)
                h[kk] = *(const float4*)&h0[kb + kk][j];
            float4 w[4];
#pragma unroll
            for (int jj = 0; jj < 4; ++jj)
                w[jj] = *(const float4*)&w2[(j + jj)*HID + cb];
#pragma unroll
            for (int jj = 0; jj < 4; ++jj)
#pragma unroll
                for (int ci = 0; ci < 4; ++ci) {
                    const float wv = F4C(w[jj], ci);
#pragma unroll
                    for (int kk = 0; kk < 8; ++kk)
                        acc[ci][kk] = fmaf(F4C(h[kk], jj), wv, acc[ci][kk]);
                }
        }
    }
    __syncthreads();                                 // h0 reads done; reuse as scratch

    // per-thread partial sums over its 8 k's (k ascending within group)
    {
        float4 part;
#pragma unroll
        for (int ci = 0; ci < 4; ++ci) {
            float p = acc[ci][0];
#pragma unroll
            for (int kk = 1; kk < 8; ++kk) p += acc[ci][kk];
            if (ci == 0) part.x = p; else if (ci == 1) part.y = p;
            else if (ci == 2) part.z = p; else part.w = p;
        }
        ((float4*)h0)[t] = part;                     // [kt][ct] -> flat t
    }
    __syncthreads();

    // cross-k-group reduce (kt ascending) + bias + mean, wave 0 writes out
    if (t < 64) {
        const float4 p0 = ((const float4*)h0)[  0 + t];
        const float4 p1 = ((const float4*)h0)[ 64 + t];
        const float4 p2 = ((const float4*)h0)[128 + t];
        const float4 p3 = ((const float4*)h0)[192 + t];
        const float4 bv = *(const float4*)&b2[4 * t];
        float4 o;
        o.x = fmaf(((p0.x + p1.x) + p2.x) + p3.x, 1.0f / KK, bv.x);
        o.y = fmaf(((p0.y + p1.y) + p2.y) + p3.y, 1.0f / KK, bv.y);
        o.z = fmaf(((p0.z + p1.z) + p2.z) + p3.z, 1.0f / KK, bv.z);
        o.w = fmaf(((p0.w + p1.w) + p2.w) + p3.w, 1.0f / KK, bv.w);
        *(float4*)&out[(size_t)bs * HID + 4 * t] = o;
    }
}

extern "C" void kernel_launch(void* const* d_in, const int* in_sizes, int n_in,
                              void* d_out, int out_size, void* d_ws, size_t ws_size,
                              hipStream_t stream) {
    const float* pos  = (const float*)d_in[0];
    const int*   sni  = (const int*)  d_in[1];
    const float* w_in = (const float*)d_in[2];
    const float* b_in = (const float*)d_in[3];
    const float* w1   = (const float*)d_in[4];
    const float* b1   = (const float*)d_in[5];
    const float* w2   = (const float*)d_in[6];
    const float* b2   = (const float*)d_in[7];
    float* out = (float*)d_out;
    (void)d_ws; (void)ws_size; (void)in_sizes; (void)n_in; (void)out_size;

    dim3 grid(BB * SS), block(NTH);
    hipLaunchKernelGGL(snp_kernel, grid, block, 0, stream,
                       pos, sni, w_in, b_in, w1, b1, w2, b2, out);
}